// Round 1
// baseline (504.136 us; speedup 1.0000x reference)
//
#include <hip/hip_runtime.h>

// Problem constants (match reference)
#define N_PTS   1000000
#define C_DIM   128
#define B_DIM   8
#define Y_DIM   468
#define X_DIM   468
#define YX      (Y_DIM * X_DIM)         // 219024
#define KSPACE  (B_DIM * YX)            // 1752192 dense key space

// Scan config
#define WG   256
#define EPT  8
#define EPB  (WG * EPT)                 // 2048 elements per scan block
#define NBLK ((KSPACE + EPB - 1) / EPB) // 856

__device__ __forceinline__ unsigned long long shfl_up_u64(unsigned long long v, int delta) {
    unsigned lo = (unsigned)v;
    unsigned hi = (unsigned)(v >> 32);
    lo = __shfl_up(lo, delta, 64);
    hi = __shfl_up(hi, delta, 64);
    return ((unsigned long long)hi << 32) | lo;
}

// ---------------------------------------------------------------- zero
__global__ void zero_u32(unsigned* __restrict__ p, int n) {
    int i = blockIdx.x * blockDim.x + threadIdx.x;
    if (i < n) p[i] = 0u;
}

// ---------------------------------------------------------------- histogram + key cache
__global__ void hist_kernel(const int* __restrict__ idx, unsigned* __restrict__ cnt,
                            unsigned* __restrict__ keys, int n) {
    int i = blockIdx.x * blockDim.x + threadIdx.x;
    if (i >= n) return;
    int4 v = ((const int4*)idx)[i];          // (b, z, y, x)
    unsigned key = (unsigned)(v.x * YX + v.z * X_DIM + v.w);
    keys[i] = key;
    atomicAdd(&cnt[key], 1u);
}

// ---------------------------------------------------------------- scan pass 1: per-block exclusive scan of (presence<<32)|count
__global__ void scan1_kernel(const unsigned* __restrict__ cnt,
                             unsigned long long* __restrict__ pairs,
                             unsigned long long* __restrict__ bsums, int K) {
    int base = blockIdx.x * EPB + threadIdx.x * EPT;
    unsigned long long p[EPT];
    unsigned long long run = 0;
#pragma unroll
    for (int j = 0; j < EPT; ++j) {
        int k = base + j;
        unsigned c = (k < K) ? cnt[k] : 0u;
        unsigned long long pr = (unsigned long long)c | ((unsigned long long)(c ? 1u : 0u) << 32);
        p[j] = run;                           // exclusive within thread
        run += pr;
    }
    unsigned long long tot = run;
    // inclusive wave scan of thread totals
    int lane = threadIdx.x & 63;
    unsigned long long v = tot;
#pragma unroll
    for (int d = 1; d < 64; d <<= 1) {
        unsigned long long nv = shfl_up_u64(v, d);
        if (lane >= d) v += nv;
    }
    __shared__ unsigned long long wsum[WG / 64];
    int wid = threadIdx.x >> 6;
    if (lane == 63) wsum[wid] = v;
    __syncthreads();
    unsigned long long wexcl = 0;
    for (int w = 0; w < wid; ++w) wexcl += wsum[w];
    unsigned long long texcl = wexcl + v - tot;   // exclusive across threads in block
#pragma unroll
    for (int j = 0; j < EPT; ++j) {
        int k = base + j;
        if (k < K) pairs[k] = texcl + p[j];
    }
    if (threadIdx.x == WG - 1) bsums[blockIdx.x] = wexcl + v;  // block total
}

// ---------------------------------------------------------------- scan pass 2: exclusive scan of block sums (single block, nb <= 1024)
__global__ void scan2_kernel(unsigned long long* __restrict__ bsums, int nb) {
    int t = threadIdx.x;
    unsigned long long orig = (t < nb) ? bsums[t] : 0ull;
    unsigned long long v = orig;
    int lane = t & 63;
#pragma unroll
    for (int d = 1; d < 64; d <<= 1) {
        unsigned long long nv = shfl_up_u64(v, d);
        if (lane >= d) v += nv;
    }
    __shared__ unsigned long long ws[1024 / 64];
    int wid = t >> 6;
    if (lane == 63) ws[wid] = v;
    __syncthreads();
    unsigned long long wexcl = 0;
    for (int w = 0; w < wid; ++w) wexcl += ws[w];
    if (t < nb) bsums[t] = wexcl + v - orig;      // exclusive
    if (t == 1023) {                              // grand total -> bsums[nb]
        unsigned long long tt = 0;
        for (int w = 0; w < 1024 / 64; ++w) tt += ws[w];
        bsums[nb] = tt;
    }
}

// ---------------------------------------------------------------- scan pass 3: add block offsets
__global__ void scan3_kernel(unsigned long long* __restrict__ pairs,
                             const unsigned long long* __restrict__ bsums, int K) {
    int k = blockIdx.x * blockDim.x + threadIdx.x;
    if (k < K) pairs[k] += bsums[blockIdx.x >> 3];   // 8 thread-blocks per scan block (2048/256)
}

// ---------------------------------------------------------------- emit (start<<32)|key per unique rank + sentinel
__global__ void uniq_kernel(const unsigned* __restrict__ cnt,
                            const unsigned long long* __restrict__ pairs,
                            unsigned long long* __restrict__ usk,
                            const unsigned long long* __restrict__ total, int K, int n) {
    int k = blockIdx.x * blockDim.x + threadIdx.x;
    if (k == 0) {
        unsigned nU = (unsigned)((*total) >> 32);
        usk[nU] = ((unsigned long long)n << 32);     // sentinel: start = n
    }
    if (k < K && cnt[k] > 0) {
        unsigned long long pr = pairs[k];
        unsigned r = (unsigned)(pr >> 32);           // rank
        unsigned start = (unsigned)pr;               // bucket start
        usk[r] = ((unsigned long long)start << 32) | (unsigned)k;
    }
}

// ---------------------------------------------------------------- scatter point ids into buckets
__global__ void scatter_kernel(const unsigned* __restrict__ keys,
                               const unsigned long long* __restrict__ pairs,
                               unsigned* __restrict__ cursor,
                               unsigned* __restrict__ pointIds, int n) {
    int i = blockIdx.x * blockDim.x + threadIdx.x;
    if (i >= n) return;
    unsigned k = keys[i];
    unsigned start = (unsigned)pairs[k];
    unsigned off = atomicAdd(&cursor[k], 1u);
    pointIds[start + off] = (unsigned)i;
}

// ---------------------------------------------------------------- gather + sum: one wave per output row
__global__ void __launch_bounds__(256)
gather_kernel(const float* __restrict__ feat,
              const unsigned* __restrict__ pointIds,
              const unsigned long long* __restrict__ usk,
              const unsigned long long* __restrict__ total,
              float* __restrict__ outF, float* __restrict__ outI, int n) {
    int lane = threadIdx.x & 63;
    int wid  = threadIdx.x >> 6;
    long r = (long)blockIdx.x * 4 + wid;
    if (r >= n) return;
    unsigned nU = (unsigned)((*total) >> 32);
    float2* dst = (float2*)(outF + (size_t)r * C_DIM);
    if (r < (long)nU) {
        unsigned long long a = usk[r];
        unsigned long long b = usk[r + 1];
        unsigned start = (unsigned)(a >> 32);
        unsigned end   = (unsigned)(b >> 32);
        unsigned key   = (unsigned)a;
        float2 acc = make_float2(0.f, 0.f);
        for (unsigned j = start; j < end; ++j) {
            unsigned pid = pointIds[j];
            float2 v = ((const float2*)(feat + (size_t)pid * C_DIM))[lane];
            acc.x += v.x;
            acc.y += v.y;
        }
        dst[lane] = acc;
        if (lane == 0) {
            unsigned bb  = key / YX;
            unsigned rem = key % YX;
            outI[r * 3 + 0] = (float)bb;
            outI[r * 3 + 1] = (float)(rem / X_DIM);
            outI[r * 3 + 2] = (float)(rem % X_DIM);
        }
    } else {
        dst[lane] = make_float2(0.f, 0.f);
        if (lane == 0) {
            outI[r * 3 + 0] = -1.0f;
            outI[r * 3 + 1] = 467.0f;   // (-1 % YX) // X  per numpy floor-mod
            outI[r * 3 + 2] = 467.0f;
        }
    }
}

extern "C" void kernel_launch(void* const* d_in, const int* in_sizes, int n_in,
                              void* d_out, int out_size, void* d_ws, size_t ws_size,
                              hipStream_t stream) {
    const float* feat = (const float*)d_in[0];
    const int*   idx  = (const int*)d_in[1];
    const int n = in_sizes[0] / C_DIM;   // 1,000,000
    const int K = KSPACE;

    // workspace layout (256B aligned slices)
    char* ws = (char*)d_ws;
    size_t off = 0;
    auto take = [&](size_t bytes) {
        size_t cur = off;
        off = (off + bytes + 255) & ~(size_t)255;
        return cur;
    };
    size_t o_cnt    = take((size_t)K * 4);        // count per key
    size_t o_cursor = take((size_t)K * 4);        // scatter cursors (contiguous w/ cnt)
    size_t o_keys   = take((size_t)n * 4);        // cached keys per point
    size_t o_pairs  = take((size_t)K * 8);        // (rank<<32)|offset exclusive scan
    size_t o_bsums  = take((size_t)(NBLK + 1) * 8);
    size_t o_pids   = take((size_t)n * 4);        // point ids grouped by key
    size_t o_usk    = take((size_t)(n + 1) * 8);  // (start<<32)|key per rank

    unsigned*           cnt    = (unsigned*)(ws + o_cnt);
    unsigned*           cursor = (unsigned*)(ws + o_cursor);
    unsigned*           keys   = (unsigned*)(ws + o_keys);
    unsigned long long* pairs  = (unsigned long long*)(ws + o_pairs);
    unsigned long long* bsums  = (unsigned long long*)(ws + o_bsums);
    unsigned*           pids   = (unsigned*)(ws + o_pids);
    unsigned long long* usk    = (unsigned long long*)(ws + o_usk);

    float* outF = (float*)d_out;
    float* outI = outF + (size_t)n * C_DIM;

    // 1. zero count + cursor (contiguous: 2K u32)
    {
        int m = 2 * K;
        zero_u32<<<(m + 255) / 256, 256, 0, stream>>>(cnt, m);
    }
    // 2. histogram + cache keys
    hist_kernel<<<(n + 255) / 256, 256, 0, stream>>>(idx, cnt, keys, n);
    // 3-5. exclusive scan of (presence, count) pairs
    scan1_kernel<<<NBLK, WG, 0, stream>>>(cnt, pairs, bsums, K);
    scan2_kernel<<<1, 1024, 0, stream>>>(bsums, NBLK);
    scan3_kernel<<<(K + 255) / 256, 256, 0, stream>>>(pairs, bsums, K);
    // 6. unique (start,key) table + sentinel
    uniq_kernel<<<(K + 255) / 256, 256, 0, stream>>>(cnt, pairs, usk, bsums + NBLK, K, n);
    // 7. scatter point ids into buckets
    scatter_kernel<<<(n + 255) / 256, 256, 0, stream>>>(keys, pairs, cursor, pids, n);
    // 8. gather + sum, one wave per output row
    gather_kernel<<<(n + 3) / 4, 256, 0, stream>>>(feat, pids, usk, bsums + NBLK,
                                                   outF, outI, n);
}

// Round 2
// 374.908 us; speedup vs baseline: 1.3447x; 1.3447x over previous
//
#include <hip/hip_runtime.h>

// Problem constants (match reference)
#define N_PTS   1000000
#define C_DIM   128
#define B_DIM   8
#define Y_DIM   468
#define X_DIM   468
#define YX      (Y_DIM * X_DIM)         // 219024
#define KSPACE  (B_DIM * YX)            // 1752192 dense key space

// Scan config
#define WG   256
#define EPT  8
#define EPB  (WG * EPT)                 // 2048 elements per scan block
#define NBLK ((KSPACE + EPB - 1) / EPB) // 856

__device__ __forceinline__ unsigned long long shfl_up_u64(unsigned long long v, int delta) {
    unsigned lo = (unsigned)v;
    unsigned hi = (unsigned)(v >> 32);
    lo = __shfl_up(lo, delta, 64);
    hi = __shfl_up(hi, delta, 64);
    return ((unsigned long long)hi << 32) | lo;
}

// ---------------------------------------------------------------- zero
__global__ void zero_u32(unsigned* __restrict__ p, int n) {
    int i = blockIdx.x * blockDim.x + threadIdx.x;
    if (i < n) p[i] = 0u;
}

// ---------------------------------------------------------------- histogram + key cache
__global__ void hist_kernel(const int* __restrict__ idx, unsigned* __restrict__ cnt,
                            unsigned* __restrict__ keys, int n) {
    int i = blockIdx.x * blockDim.x + threadIdx.x;
    if (i >= n) return;
    int4 v = ((const int4*)idx)[i];          // (b, z, y, x)
    unsigned key = (unsigned)(v.x * YX + v.z * X_DIM + v.w);
    keys[i] = key;
    atomicAdd(&cnt[key], 1u);
}

// ---------------------------------------------------------------- scan pass 1: per-block exclusive scan of (presence<<32)|count
__global__ void scan1_kernel(const unsigned* __restrict__ cnt,
                             unsigned long long* __restrict__ pairs,
                             unsigned long long* __restrict__ bsums, int K) {
    int base = blockIdx.x * EPB + threadIdx.x * EPT;
    unsigned long long p[EPT];
    unsigned long long run = 0;
#pragma unroll
    for (int j = 0; j < EPT; ++j) {
        int k = base + j;
        unsigned c = (k < K) ? cnt[k] : 0u;
        unsigned long long pr = (unsigned long long)c | ((unsigned long long)(c ? 1u : 0u) << 32);
        p[j] = run;                           // exclusive within thread
        run += pr;
    }
    unsigned long long tot = run;
    // inclusive wave scan of thread totals
    int lane = threadIdx.x & 63;
    unsigned long long v = tot;
#pragma unroll
    for (int d = 1; d < 64; d <<= 1) {
        unsigned long long nv = shfl_up_u64(v, d);
        if (lane >= d) v += nv;
    }
    __shared__ unsigned long long wsum[WG / 64];
    int wid = threadIdx.x >> 6;
    if (lane == 63) wsum[wid] = v;
    __syncthreads();
    unsigned long long wexcl = 0;
    for (int w = 0; w < wid; ++w) wexcl += wsum[w];
    unsigned long long texcl = wexcl + v - tot;   // exclusive across threads in block
#pragma unroll
    for (int j = 0; j < EPT; ++j) {
        int k = base + j;
        if (k < K) pairs[k] = texcl + p[j];
    }
    if (threadIdx.x == WG - 1) bsums[blockIdx.x] = wexcl + v;  // block total
}

// ---------------------------------------------------------------- scan pass 2: exclusive scan of block sums (single block, nb <= 1024)
__global__ void scan2_kernel(unsigned long long* __restrict__ bsums, int nb) {
    int t = threadIdx.x;
    unsigned long long orig = (t < nb) ? bsums[t] : 0ull;
    unsigned long long v = orig;
    int lane = t & 63;
#pragma unroll
    for (int d = 1; d < 64; d <<= 1) {
        unsigned long long nv = shfl_up_u64(v, d);
        if (lane >= d) v += nv;
    }
    __shared__ unsigned long long ws[1024 / 64];
    int wid = t >> 6;
    if (lane == 63) ws[wid] = v;
    __syncthreads();
    unsigned long long wexcl = 0;
    for (int w = 0; w < wid; ++w) wexcl += ws[w];
    if (t < nb) bsums[t] = wexcl + v - orig;      // exclusive
    if (t == 1023) {                              // grand total -> bsums[nb]
        unsigned long long tt = 0;
        for (int w = 0; w < 1024 / 64; ++w) tt += ws[w];
        bsums[nb] = tt;
    }
}

// ---------------------------------------------------------------- emit rowdesc[rank] = {start, end, key, 0} (fused scan3: adds bsums on the fly)
__global__ void uniq_kernel(const unsigned* __restrict__ cnt,
                            const unsigned long long* __restrict__ pairs,
                            const unsigned long long* __restrict__ bsums,
                            uint4* __restrict__ rowdesc, int K) {
    int k = blockIdx.x * blockDim.x + threadIdx.x;
    if (k >= K) return;
    unsigned c = cnt[k];
    if (c == 0) return;
    unsigned long long pr = pairs[k] + bsums[k >> 11];   // EPB = 2048
    unsigned r     = (unsigned)(pr >> 32);               // rank
    unsigned start = (unsigned)pr;                       // bucket start
    rowdesc[r] = make_uint4(start, start + c, (unsigned)k, 0u);
}

// ---------------------------------------------------------------- scatter point ids into buckets (adds bsums on the fly)
__global__ void scatter_kernel(const unsigned* __restrict__ keys,
                               const unsigned long long* __restrict__ pairs,
                               const unsigned long long* __restrict__ bsums,
                               unsigned* __restrict__ cursor,
                               unsigned* __restrict__ pointIds, int n) {
    int i = blockIdx.x * blockDim.x + threadIdx.x;
    if (i >= n) return;
    unsigned k = keys[i];
    unsigned start = (unsigned)(pairs[k] + bsums[k >> 11]);
    unsigned off = atomicAdd(&cursor[k], 1u);
    pointIds[start + off] = (unsigned)i;
}

// ---------------------------------------------------------------- gather + sum: 2 rows per wave, 32 lanes x float4 per row
__global__ void __launch_bounds__(256)
gather_kernel(const float* __restrict__ feat,
              const unsigned* __restrict__ pointIds,
              const uint4* __restrict__ rowdesc,
              const unsigned long long* __restrict__ total,
              float* __restrict__ outF, float* __restrict__ outI, int n) {
    int lane = threadIdx.x & 63;
    int wid  = threadIdx.x >> 6;
    int half = lane >> 5;                 // which of the 2 rows this lane serves
    int sub  = lane & 31;                 // float4 slot within the row
    long r = (long)blockIdx.x * 8 + wid * 2 + half;
    if (r >= n) return;
    uint4 d = rowdesc[r];                 // garbage if r >= nU (never used then)
    unsigned nU = (unsigned)((*total) >> 32);
    float4* dst = (float4*)(outF + (size_t)r * C_DIM) + sub;
    if (r < (long)nU) {
        float4 acc = make_float4(0.f, 0.f, 0.f, 0.f);
        for (unsigned j = d.x; j < d.y; ++j) {
            unsigned pid = pointIds[j];
            float4 v = ((const float4*)(feat + (size_t)pid * C_DIM))[sub];
            acc.x += v.x; acc.y += v.y; acc.z += v.z; acc.w += v.w;
        }
        *dst = acc;
        if (sub == 0) {
            unsigned key = d.z;
            unsigned bb  = key / YX;
            unsigned rem = key % YX;
            outI[r * 3 + 0] = (float)bb;
            outI[r * 3 + 1] = (float)(rem / X_DIM);
            outI[r * 3 + 2] = (float)(rem % X_DIM);
        }
    } else {
        *dst = make_float4(0.f, 0.f, 0.f, 0.f);
        if (sub == 0) {
            outI[r * 3 + 0] = -1.0f;
            outI[r * 3 + 1] = 467.0f;     // (-1 % YX) // X per numpy floor-mod
            outI[r * 3 + 2] = 467.0f;
        }
    }
}

extern "C" void kernel_launch(void* const* d_in, const int* in_sizes, int n_in,
                              void* d_out, int out_size, void* d_ws, size_t ws_size,
                              hipStream_t stream) {
    const float* feat = (const float*)d_in[0];
    const int*   idx  = (const int*)d_in[1];
    const int n = in_sizes[0] / C_DIM;   // 1,000,000
    const int K = KSPACE;

    // workspace layout (256B aligned slices)
    char* ws = (char*)d_ws;
    size_t off = 0;
    auto take = [&](size_t bytes) {
        size_t cur = off;
        off = (off + bytes + 255) & ~(size_t)255;
        return cur;
    };
    size_t o_cnt    = take((size_t)K * 4);        // count per key
    size_t o_cursor = take((size_t)K * 4);        // scatter cursors (contiguous w/ cnt)
    size_t o_keys   = take((size_t)n * 4);        // cached keys per point
    size_t o_pairs  = take((size_t)K * 8);        // (rank<<32)|offset partial scan
    size_t o_bsums  = take((size_t)(NBLK + 1) * 8);
    size_t o_pids   = take((size_t)n * 4);        // point ids grouped by key
    size_t o_desc   = take((size_t)n * 16);       // rowdesc {start,end,key,0} per rank

    unsigned*           cnt    = (unsigned*)(ws + o_cnt);
    unsigned*           cursor = (unsigned*)(ws + o_cursor);
    unsigned*           keys   = (unsigned*)(ws + o_keys);
    unsigned long long* pairs  = (unsigned long long*)(ws + o_pairs);
    unsigned long long* bsums  = (unsigned long long*)(ws + o_bsums);
    unsigned*           pids   = (unsigned*)(ws + o_pids);
    uint4*              desc   = (uint4*)(ws + o_desc);

    float* outF = (float*)d_out;
    float* outI = outF + (size_t)n * C_DIM;

    // 1. zero count + cursor (contiguous: 2K u32)
    {
        int m = 2 * K;
        zero_u32<<<(m + 255) / 256, 256, 0, stream>>>(cnt, m);
    }
    // 2. histogram + cache keys
    hist_kernel<<<(n + 255) / 256, 256, 0, stream>>>(idx, cnt, keys, n);
    // 3-4. two-level exclusive scan of (presence, count) pairs
    scan1_kernel<<<NBLK, WG, 0, stream>>>(cnt, pairs, bsums, K);
    scan2_kernel<<<1, 1024, 0, stream>>>(bsums, NBLK);
    // 5. unique rowdesc table (fused block-offset add)
    uniq_kernel<<<(K + 255) / 256, 256, 0, stream>>>(cnt, pairs, bsums, desc, K);
    // 6. scatter point ids into buckets (fused block-offset add)
    scatter_kernel<<<(n + 255) / 256, 256, 0, stream>>>(keys, pairs, bsums, cursor, pids, n);
    // 7. gather + sum, 2 rows per wave
    gather_kernel<<<(n + 7) / 8, 256, 0, stream>>>(feat, pids, desc, bsums + NBLK,
                                                   outF, outI, n);
}